// Round 1
// baseline (585.979 us; speedup 1.0000x reference)
//
#include <hip/hip_runtime.h>
#include <hip/hip_bf16.h>
#include <cstdint>
#include <cstddef>

#define DM   256
#define DI   512
#define DTR  16
#define DS   16
#define LSEQ 4096
#define BATCH 2
#define BLROWS (BATCH * LSEQ)   /* 8192 */
#define NCH  64                 /* chunks per sequence */
#define CLEN 64                 /* steps per chunk */

typedef __bf16 bf16x8 __attribute__((ext_vector_type(8)));
typedef float  f32x4  __attribute__((ext_vector_type(4)));

__device__ __forceinline__ unsigned short f2bfu(float f) {
    union { float f; unsigned u; } c; c.f = f;
    unsigned u = c.u;
    return (unsigned short)((u + 0x7fffu + ((u >> 16) & 1u)) >> 16);
}

__device__ __forceinline__ float siluf(float v) {
    return v * (1.0f / (1.0f + __expf(-v)));
}

/* ---------------- casts ---------------- */
__global__ __launch_bounds__(256) void cast_f32_bf16_k(
    const float* __restrict__ s, unsigned short* __restrict__ d, int n) {
    int i = blockIdx.x * 256 + threadIdx.x;
    if (i < n) d[i] = f2bfu(s[i]);
}

/* pad x_proj_w [2,48,512] -> [2,64,512] bf16 (rows 48..63 zero) */
__global__ __launch_bounds__(256) void cast_xp_pad_k(
    const float* __restrict__ s, unsigned short* __restrict__ d) {
    int i = blockIdx.x * 256 + threadIdx.x;     /* 2*64*512 = 65536 */
    int k = i & 511, o = (i >> 9) & 63, l = i >> 15;
    float v = (o < 48) ? s[(l * 48 + o) * 512 + k] : 0.0f;
    d[i] = f2bfu(v);
}

/* ---------------- bf16 MFMA GEMM:  C[M,N] = A[M,K] * B[N,K]^T  ---------------- */
/* block = 256 thr (4 waves); block tile 64x64; wave tile 32x32 (2x2 mfma 16x16x32) */
__global__ __launch_bounds__(256) void gemm_bt_k(
    const __bf16* __restrict__ A, const __bf16* __restrict__ B,
    float* __restrict__ C, int M, int N, int K) {
    int tid  = threadIdx.x;
    int wave = tid >> 6, lane = tid & 63;
    int row  = lane & 15, q = lane >> 4;           /* q in 0..3 */
    int bm = blockIdx.x * 64, bn = blockIdx.y * 64;
    int wm = bm + (wave & 1) * 32, wn = bn + (wave >> 1) * 32;
    f32x4 acc00 = {0.f,0.f,0.f,0.f}, acc01 = acc00, acc10 = acc00, acc11 = acc00;
    const bf16x8* Av = (const bf16x8*)A;
    const bf16x8* Bv = (const bf16x8*)B;
    int sA = K >> 3, sB = K >> 3;
    for (int k0 = 0; k0 < K; k0 += 32) {
        int kb = (k0 >> 3) + q;                    /* 8-elem group index */
        bf16x8 a0 = Av[(size_t)(wm + row)      * sA + kb];
        bf16x8 a1 = Av[(size_t)(wm + 16 + row) * sA + kb];
        bf16x8 b0 = Bv[(size_t)(wn + row)      * sB + kb];
        bf16x8 b1 = Bv[(size_t)(wn + 16 + row) * sB + kb];
        acc00 = __builtin_amdgcn_mfma_f32_16x16x32_bf16(a0, b0, acc00, 0, 0, 0);
        acc01 = __builtin_amdgcn_mfma_f32_16x16x32_bf16(a0, b1, acc01, 0, 0, 0);
        acc10 = __builtin_amdgcn_mfma_f32_16x16x32_bf16(a1, b0, acc10, 0, 0, 0);
        acc11 = __builtin_amdgcn_mfma_f32_16x16x32_bf16(a1, b1, acc11, 0, 0, 0);
    }
    /* C/D layout: col = lane&15, row = q*4 + r  (learn_hip m89-verified) */
    #pragma unroll
    for (int r = 0; r < 4; ++r) {
        C[(size_t)(wm + q*4 + r)      * N + wn + row]      = acc00[r];
        C[(size_t)(wm + q*4 + r)      * N + wn + 16 + row] = acc01[r];
        C[(size_t)(wm + 16 + q*4 + r) * N + wn + row]      = acc10[r];
        C[(size_t)(wm + 16 + q*4 + r) * N + wn + 16 + row] = acc11[r];
    }
}

/* ---------------- causal depthwise conv (taps=4) + bias + silu ---------------- */
__global__ __launch_bounds__(256) void conv_silu_k(
    const float* __restrict__ xz, const float* __restrict__ cw,
    const float* __restrict__ cb, float* __restrict__ xc,
    unsigned short* __restrict__ xcb) {
    int i = blockIdx.x * 256 + threadIdx.x;   /* BLROWS*DI */
    int d = i & (DI - 1); int bl = i >> 9;
    int l = bl & (LSEQ - 1);
    float acc = cb[d];
    #pragma unroll
    for (int j = 0; j < 4; ++j) {
        int ll = l - 3 + j;
        if (ll >= 0) acc = fmaf(xz[(size_t)(bl - 3 + j) * (2*DI) + d], cw[d*4 + j], acc);
    }
    float v = siluf(acc);
    xc[i] = v;
    xcb[i] = f2bfu(v);
}

/* ---------------- dt = softplus(xdbl[:, :16] @ dt_w^T + dt_b) ---------------- */
__global__ __launch_bounds__(256) void dt_k(
    const float* __restrict__ xdbl, const float* __restrict__ dtw,
    const float* __restrict__ dtb, float* __restrict__ dt) {
    int i = blockIdx.x * 256 + threadIdx.x;   /* BLROWS*DI */
    int d = i & (DI - 1); int bl = i >> 9;
    float acc = dtb[d];
    const float* xr = xdbl + (size_t)bl * 64;
    #pragma unroll
    for (int r = 0; r < 16; ++r) acc = fmaf(xr[r], dtw[d*16 + r], acc);
    dt[i] = (acc > 20.0f) ? acc : logf(1.0f + __expf(acc));
}

/* ---------------- scan phase A: per-chunk (P = prod dA, S = local scan) ------- */
__global__ __launch_bounds__(256) void scanA_k(
    const float* __restrict__ dt, const float* __restrict__ xc,
    const float* __restrict__ xdbl, const float* __restrict__ Alog,
    float* __restrict__ P, float* __restrict__ S) {
    int n = threadIdx.x & 15, dl = threadIdx.x >> 4;
    int d = blockIdx.x * 16 + dl;
    int c = blockIdx.y, b = blockIdx.z;
    float Ac = -__expf(Alog[d*16 + n]);
    float p = 1.0f, s = 0.0f;
    int l0 = c * CLEN;
    for (int t = 0; t < CLEN; ++t) {
        size_t bl = (size_t)b * LSEQ + l0 + t;
        float dtv = dt[bl*DI + d];
        float xv  = xc[bl*DI + d];
        float Bv  = xdbl[bl*64 + 16 + n];
        float a = __expf(dtv * Ac);
        s = fmaf(a, s, dtv * Bv * xv);
        p *= a;
    }
    size_t idx = ((size_t)(b*NCH + c)*DI + d)*16 + n;
    P[idx] = p; S[idx] = s;
}

/* ---------------- scan phase B: stitch chunk entry states ---------------- */
__global__ __launch_bounds__(256) void scanB_k(
    const float* __restrict__ P, const float* __restrict__ S,
    float* __restrict__ H) {
    int i = blockIdx.x * 256 + threadIdx.x;   /* BATCH*DI*DS = 16384 */
    int b = i >> 13, j = i & 8191;
    float h = 0.0f;
    for (int c = 0; c < NCH; ++c) {
        size_t idx = (size_t)(b*NCH + c) * 8192 + j;
        H[idx] = h;
        h = fmaf(P[idx], h, S[idx]);
    }
}

/* ---------------- scan phase C: replay chunk, emit y*silu(gate) as bf16 ------- */
__global__ __launch_bounds__(256) void scanC_k(
    const float* __restrict__ dt, const float* __restrict__ xc,
    const float* __restrict__ xdbl, const float* __restrict__ H,
    const float* __restrict__ Alog, const float* __restrict__ Dp,
    const float* __restrict__ xz, unsigned short* __restrict__ yout) {
    int n = threadIdx.x & 15, dl = threadIdx.x >> 4;
    int d = blockIdx.x * 16 + dl;
    int c = blockIdx.y, b = blockIdx.z;
    float Ac = -__expf(Alog[d*16 + n]);
    float Dv = Dp[d];
    float h = H[((size_t)(b*NCH + c)*DI + d)*16 + n];
    int l0 = c * CLEN;
    for (int t = 0; t < CLEN; ++t) {
        size_t bl = (size_t)b * LSEQ + l0 + t;
        float dtv = dt[bl*DI + d];
        float xv  = xc[bl*DI + d];
        float Bv  = xdbl[bl*64 + 16 + n];
        float Cv  = xdbl[bl*64 + 32 + n];
        float a = __expf(dtv * Ac);
        h = fmaf(a, h, dtv * Bv * xv);
        float y = h * Cv;
        y += __shfl_xor(y, 1, 64);
        y += __shfl_xor(y, 2, 64);
        y += __shfl_xor(y, 4, 64);
        y += __shfl_xor(y, 8, 64);
        if (n == 0) {
            float g = xz[bl*(2*DI) + DI + d];
            float yv = (y + xv * Dv) * siluf(g);
            yout[bl*DI + d] = f2bfu(yv);
        }
    }
}

/* ================================================================== */
extern "C" void kernel_launch(void* const* d_in, const int* in_sizes, int n_in,
                              void* d_out, int out_size, void* d_ws, size_t ws_size,
                              hipStream_t stream) {
    (void)in_sizes; (void)n_in; (void)out_size; (void)ws_size;
    const float* z_in   = (const float*)d_in[0];
    const float* in_w   = (const float*)d_in[1];
    const float* conv_w = (const float*)d_in[2];
    const float* conv_b = (const float*)d_in[3];
    const float* xp_w   = (const float*)d_in[4];
    const float* dt_w   = (const float*)d_in[5];
    const float* dt_b   = (const float*)d_in[6];
    const float* A_log  = (const float*)d_in[7];
    const float* D_par  = (const float*)d_in[8];
    const float* out_w  = (const float*)d_in[9];
    float* outp = (float*)d_out;

    char* p = (char*)d_ws;
    auto alloc = [&](size_t bytes) { char* r = p; p += (bytes + 255) & ~(size_t)255; return r; };
    unsigned short* z_bf    = (unsigned short*)alloc((size_t)BLROWS*DM*2);
    unsigned short* xc_bf   = (unsigned short*)alloc((size_t)BLROWS*DI*2);
    unsigned short* y_bf    = (unsigned short*)alloc((size_t)BLROWS*DI*2);
    unsigned short* inw_bf  = (unsigned short*)alloc((size_t)2*1024*256*2);
    unsigned short* outw_bf = (unsigned short*)alloc((size_t)2*256*512*2);
    unsigned short* xpw_bf  = (unsigned short*)alloc((size_t)2*64*512*2);
    float* xz     = (float*)alloc((size_t)BLROWS*1024*4);
    float* x_conv = (float*)alloc((size_t)BLROWS*DI*4);
    float* x_dbl  = (float*)alloc((size_t)BLROWS*64*4);
    float* dtbuf  = (float*)alloc((size_t)BLROWS*DI*4);
    float* Pbuf   = (float*)alloc((size_t)BATCH*NCH*DI*DS*4);
    float* Sbuf   = (float*)alloc((size_t)BATCH*NCH*DI*DS*4);
    float* Hbuf   = (float*)alloc((size_t)BATCH*NCH*DI*DS*4);
    float* z_next = (float*)alloc((size_t)BLROWS*DM*4);

    /* weight casts (once per launch) */
    cast_f32_bf16_k<<<(2*1024*256)/256, 256, 0, stream>>>(in_w, inw_bf, 2*1024*256);
    cast_f32_bf16_k<<<(2*256*512)/256, 256, 0, stream>>>(out_w, outw_bf, 2*256*512);
    cast_xp_pad_k<<<(2*64*512)/256, 256, 0, stream>>>(xp_w, xpw_bf);

    const float* zcur = z_in;
    for (int l = 0; l < 2; ++l) {
        cast_f32_bf16_k<<<(BLROWS*DM)/256, 256, 0, stream>>>(zcur, z_bf, BLROWS*DM);
        /* in_proj: [8192,1024] = z[8192,256] @ in_w[1024,256]^T */
        gemm_bt_k<<<dim3(BLROWS/64, 1024/64), 256, 0, stream>>>(
            (const __bf16*)z_bf, (const __bf16*)(inw_bf + (size_t)l*1024*256),
            xz, BLROWS, 1024, 256);
        conv_silu_k<<<(BLROWS*DI)/256, 256, 0, stream>>>(
            xz, conv_w + (size_t)l*DI*4, conv_b + (size_t)l*DI, x_conv, xc_bf);
        /* x_proj (padded to 64 outputs): [8192,64] = xc[8192,512] @ xpw[64,512]^T */
        gemm_bt_k<<<dim3(BLROWS/64, 1), 256, 0, stream>>>(
            (const __bf16*)xc_bf, (const __bf16*)(xpw_bf + (size_t)l*64*512),
            x_dbl, BLROWS, 64, 512);
        dt_k<<<(BLROWS*DI)/256, 256, 0, stream>>>(
            x_dbl, dt_w + (size_t)l*DI*DTR, dt_b + (size_t)l*DI, dtbuf);
        scanA_k<<<dim3(DI/16, NCH, BATCH), 256, 0, stream>>>(
            dtbuf, x_conv, x_dbl, A_log + (size_t)l*DI*DS, Pbuf, Sbuf);
        scanB_k<<<(BATCH*DI*DS)/256, 256, 0, stream>>>(Pbuf, Sbuf, Hbuf);
        scanC_k<<<dim3(DI/16, NCH, BATCH), 256, 0, stream>>>(
            dtbuf, x_conv, x_dbl, Hbuf, A_log + (size_t)l*DI*DS,
            D_par + (size_t)l*DI, xz, y_bf);
        /* out_proj: [8192,256] = y[8192,512] @ out_w[256,512]^T */
        gemm_bt_k<<<dim3(BLROWS/64, 256/64), 256, 0, stream>>>(
            (const __bf16*)y_bf, (const __bf16*)(outw_bf + (size_t)l*256*512),
            (l == 0) ? z_next : outp, BLROWS, 256, 512);
        zcur = z_next;
    }
}

// Round 2
// 450.283 us; speedup vs baseline: 1.3014x; 1.3014x over previous
//
#include <hip/hip_runtime.h>
#include <hip/hip_bf16.h>
#include <cstdint>
#include <cstddef>

#define DM   256
#define DI   512
#define DTR  16
#define DS   16
#define LSEQ 4096
#define BATCH 2
#define BLROWS (BATCH * LSEQ)   /* 8192 */
#define NCH  128                /* chunks per sequence */
#define CLEN 32                 /* steps per chunk */

typedef __bf16 bf16x8 __attribute__((ext_vector_type(8)));
typedef float  f32x4  __attribute__((ext_vector_type(4)));

__device__ __forceinline__ unsigned short f2bfu(float f) {
    union { float f; unsigned u; } c; c.f = f;
    unsigned u = c.u;
    return (unsigned short)((u + 0x7fffu + ((u >> 16) & 1u)) >> 16);
}

__device__ __forceinline__ float siluf(float v) {
    return v * (1.0f / (1.0f + __expf(-v)));
}

/* ---------------- casts ---------------- */
__global__ __launch_bounds__(256) void cast_f32_bf16_k(
    const float* __restrict__ s, unsigned short* __restrict__ d, int n) {
    int i = blockIdx.x * 256 + threadIdx.x;
    if (i < n) d[i] = f2bfu(s[i]);
}

/* pad x_proj_w [2,48,512] -> [2,64,512] bf16 (rows 48..63 zero) */
__global__ __launch_bounds__(256) void cast_xp_pad_k(
    const float* __restrict__ s, unsigned short* __restrict__ d) {
    int i = blockIdx.x * 256 + threadIdx.x;     /* 2*64*512 = 65536 */
    int k = i & 511, o = (i >> 9) & 63, l = i >> 15;
    float v = (o < 48) ? s[(l * 48 + o) * 512 + k] : 0.0f;
    d[i] = f2bfu(v);
}

/* ---------------- bf16 MFMA GEMM:  C[M,N] = A[M,K] * B[N,K]^T  ---------------- */
__global__ __launch_bounds__(256) void gemm_bt_k(
    const __bf16* __restrict__ A, const __bf16* __restrict__ B,
    float* __restrict__ C, int M, int N, int K) {
    int tid  = threadIdx.x;
    int wave = tid >> 6, lane = tid & 63;
    int row  = lane & 15, q = lane >> 4;           /* q in 0..3 */
    int bm = blockIdx.x * 64, bn = blockIdx.y * 64;
    int wm = bm + (wave & 1) * 32, wn = bn + (wave >> 1) * 32;
    f32x4 acc00 = {0.f,0.f,0.f,0.f}, acc01 = acc00, acc10 = acc00, acc11 = acc00;
    const bf16x8* Av = (const bf16x8*)A;
    const bf16x8* Bv = (const bf16x8*)B;
    int sA = K >> 3, sB = K >> 3;
    for (int k0 = 0; k0 < K; k0 += 32) {
        int kb = (k0 >> 3) + q;                    /* 8-elem group index */
        bf16x8 a0 = Av[(size_t)(wm + row)      * sA + kb];
        bf16x8 a1 = Av[(size_t)(wm + 16 + row) * sA + kb];
        bf16x8 b0 = Bv[(size_t)(wn + row)      * sB + kb];
        bf16x8 b1 = Bv[(size_t)(wn + 16 + row) * sB + kb];
        acc00 = __builtin_amdgcn_mfma_f32_16x16x32_bf16(a0, b0, acc00, 0, 0, 0);
        acc01 = __builtin_amdgcn_mfma_f32_16x16x32_bf16(a0, b1, acc01, 0, 0, 0);
        acc10 = __builtin_amdgcn_mfma_f32_16x16x32_bf16(a1, b0, acc10, 0, 0, 0);
        acc11 = __builtin_amdgcn_mfma_f32_16x16x32_bf16(a1, b1, acc11, 0, 0, 0);
    }
    /* C/D layout: col = lane&15, row = q*4 + r */
    #pragma unroll
    for (int r = 0; r < 4; ++r) {
        C[(size_t)(wm + q*4 + r)      * N + wn + row]      = acc00[r];
        C[(size_t)(wm + q*4 + r)      * N + wn + 16 + row] = acc01[r];
        C[(size_t)(wm + 16 + q*4 + r) * N + wn + row]      = acc10[r];
        C[(size_t)(wm + 16 + q*4 + r) * N + wn + 16 + row] = acc11[r];
    }
}

/* ---------------- causal depthwise conv (taps=4) + bias + silu ---------------- */
__global__ __launch_bounds__(256) void conv_silu_k(
    const float* __restrict__ xz, const float* __restrict__ cw,
    const float* __restrict__ cb, float* __restrict__ xc,
    unsigned short* __restrict__ xcb) {
    int i = blockIdx.x * 256 + threadIdx.x;   /* BLROWS*DI */
    int d = i & (DI - 1); int bl = i >> 9;
    int l = bl & (LSEQ - 1);
    float acc = cb[d];
    #pragma unroll
    for (int j = 0; j < 4; ++j) {
        int ll = l - 3 + j;
        if (ll >= 0) acc = fmaf(xz[(size_t)(bl - 3 + j) * (2*DI) + d], cw[d*4 + j], acc);
    }
    float v = siluf(acc);
    xc[i] = v;
    xcb[i] = f2bfu(v);
}

/* ---------------- dt = softplus(xdbl[:, :16] @ dt_w^T + dt_b) ---------------- */
__global__ __launch_bounds__(256) void dt_k(
    const float* __restrict__ xdbl, const float* __restrict__ dtw,
    const float* __restrict__ dtb, float* __restrict__ dt) {
    int i = blockIdx.x * 256 + threadIdx.x;   /* BLROWS*DI */
    int d = i & (DI - 1); int bl = i >> 9;
    float acc = dtb[d];
    const float* xr = xdbl + (size_t)bl * 64;
    #pragma unroll
    for (int r = 0; r < 16; ++r) acc = fmaf(xr[r], dtw[d*16 + r], acc);
    dt[i] = (acc > 20.0f) ? acc : logf(1.0f + __expf(acc));
}

/* ---------------- scan phase A: thread-per-d, 16 n-states in registers -------- */
/* grid: (DI/256, NCH, BATCH), block 256. Computes P = prod dA, S = local scan. */
__global__ __launch_bounds__(256) void scanA_k(
    const float* __restrict__ dt, const float* __restrict__ xc,
    const float* __restrict__ xdbl, const float* __restrict__ Alog,
    float* __restrict__ P, float* __restrict__ S) {
    __shared__ float Bs[CLEN * 16];
    int tid = threadIdx.x;
    int c = blockIdx.y, b = blockIdx.z;
    int d = blockIdx.x * 256 + tid;
    int bl0 = b * LSEQ + c * CLEN;
    /* stage B[t][n] slab */
    #pragma unroll
    for (int idx = tid; idx < CLEN * 16; idx += 256)
        Bs[idx] = xdbl[(size_t)(bl0 + (idx >> 4)) * 64 + 16 + (idx & 15)];
    __syncthreads();
    float Ac[16], p[16], s[16];
    const f32x4* Av4 = (const f32x4*)(Alog + (size_t)d * 16);
    #pragma unroll
    for (int g = 0; g < 4; ++g) {
        f32x4 v = Av4[g];
        #pragma unroll
        for (int j = 0; j < 4; ++j) {
            Ac[g*4+j] = -__expf(v[j]); p[g*4+j] = 1.0f; s[g*4+j] = 0.0f;
        }
    }
    const float* dtp = dt + (size_t)bl0 * DI + d;
    const float* xcp = xc + (size_t)bl0 * DI + d;
    for (int t = 0; t < CLEN; ++t) {
        float dtv = dtp[(size_t)t * DI];
        float xv  = xcp[(size_t)t * DI];
        float dx  = dtv * xv;
        const f32x4* Bv4 = (const f32x4*)(Bs + t * 16);
        #pragma unroll
        for (int g = 0; g < 4; ++g) {
            f32x4 Bv = Bv4[g];
            #pragma unroll
            for (int j = 0; j < 4; ++j) {
                int n = g*4 + j;
                float a = __expf(dtv * Ac[n]);
                s[n] = fmaf(a, s[n], Bv[j] * dx);
                p[n] *= a;
            }
        }
    }
    f32x4* Pp = (f32x4*)(P + ((size_t)(b*NCH + c) * DI + d) * 16);
    f32x4* Sp = (f32x4*)(S + ((size_t)(b*NCH + c) * DI + d) * 16);
    #pragma unroll
    for (int g = 0; g < 4; ++g) {
        Pp[g] = (f32x4){p[g*4], p[g*4+1], p[g*4+2], p[g*4+3]};
        Sp[g] = (f32x4){s[g*4], s[g*4+1], s[g*4+2], s[g*4+3]};
    }
}

/* ---------------- scan phase B: stitch chunk entry states (x4 vectorized) ----- */
__global__ __launch_bounds__(256) void scanB_k(
    const float* __restrict__ P, const float* __restrict__ S,
    float* __restrict__ H) {
    int i = blockIdx.x * 256 + threadIdx.x;   /* BATCH*DI*DS/4 = 4096 */
    int b = i >> 11, j4 = i & 2047;
    f32x4 h = {0.f, 0.f, 0.f, 0.f};
    for (int c = 0; c < NCH; ++c) {
        size_t idx = (size_t)(b*NCH + c) * 2048 + j4;
        f32x4 pv = ((const f32x4*)P)[idx];
        f32x4 sv = ((const f32x4*)S)[idx];
        ((f32x4*)H)[idx] = h;
        #pragma unroll
        for (int j = 0; j < 4; ++j) h[j] = fmaf(pv[j], h[j], sv[j]);
    }
}

/* ---------------- scan phase C: thread-per-d replay, emit y*silu(gate) bf16 --- */
__global__ __launch_bounds__(256) void scanC_k(
    const float* __restrict__ dt, const float* __restrict__ xc,
    const float* __restrict__ xdbl, const float* __restrict__ H,
    const float* __restrict__ Alog, const float* __restrict__ Dp,
    const float* __restrict__ xz, unsigned short* __restrict__ yout) {
    __shared__ float BCs[CLEN * 32];
    int tid = threadIdx.x;
    int c = blockIdx.y, b = blockIdx.z;
    int d = blockIdx.x * 256 + tid;
    int bl0 = b * LSEQ + c * CLEN;
    /* stage B,C slab: 32 values per t (B at 16..31, C at 32..47 of xdbl row) */
    #pragma unroll
    for (int idx = tid; idx < CLEN * 32; idx += 256)
        BCs[idx] = xdbl[(size_t)(bl0 + (idx >> 5)) * 64 + 16 + (idx & 31)];
    __syncthreads();
    float Ac[16], h[16];
    const f32x4* Av4 = (const f32x4*)(Alog + (size_t)d * 16);
    const f32x4* Hv4 = (const f32x4*)(H + ((size_t)(b*NCH + c) * DI + d) * 16);
    #pragma unroll
    for (int g = 0; g < 4; ++g) {
        f32x4 av = Av4[g]; f32x4 hv = Hv4[g];
        #pragma unroll
        for (int j = 0; j < 4; ++j) { Ac[g*4+j] = -__expf(av[j]); h[g*4+j] = hv[j]; }
    }
    float Dv = Dp[d];
    const float* dtp = dt + (size_t)bl0 * DI + d;
    const float* xcp = xc + (size_t)bl0 * DI + d;
    const float* gp  = xz + (size_t)bl0 * (2*DI) + DI + d;
    unsigned short* yp = yout + (size_t)bl0 * DI + d;
    for (int t = 0; t < CLEN; ++t) {
        float dtv = dtp[(size_t)t * DI];
        float xv  = xcp[(size_t)t * DI];
        float gv  = gp[(size_t)t * (2*DI)];
        float dx  = dtv * xv;
        const f32x4* Bv4 = (const f32x4*)(BCs + t * 32);
        const f32x4* Cv4 = (const f32x4*)(BCs + t * 32 + 16);
        float y0 = 0.f, y1 = 0.f, y2 = 0.f, y3 = 0.f;
        #pragma unroll
        for (int g = 0; g < 4; ++g) {
            f32x4 Bv = Bv4[g], Cv = Cv4[g];
            #pragma unroll
            for (int j = 0; j < 4; ++j) {
                int n = g*4 + j;
                float a = __expf(dtv * Ac[n]);
                h[n] = fmaf(a, h[n], Bv[j] * dx);
            }
            y0 = fmaf(h[g*4+0], Cv[0], y0);
            y1 = fmaf(h[g*4+1], Cv[1], y1);
            y2 = fmaf(h[g*4+2], Cv[2], y2);
            y3 = fmaf(h[g*4+3], Cv[3], y3);
        }
        float y = (y0 + y1) + (y2 + y3);
        float yv = (y + xv * Dv) * siluf(gv);
        yp[(size_t)t * DI] = f2bfu(yv);
    }
}

/* ================================================================== */
extern "C" void kernel_launch(void* const* d_in, const int* in_sizes, int n_in,
                              void* d_out, int out_size, void* d_ws, size_t ws_size,
                              hipStream_t stream) {
    (void)in_sizes; (void)n_in; (void)out_size; (void)ws_size;
    const float* z_in   = (const float*)d_in[0];
    const float* in_w   = (const float*)d_in[1];
    const float* conv_w = (const float*)d_in[2];
    const float* conv_b = (const float*)d_in[3];
    const float* xp_w   = (const float*)d_in[4];
    const float* dt_w   = (const float*)d_in[5];
    const float* dt_b   = (const float*)d_in[6];
    const float* A_log  = (const float*)d_in[7];
    const float* D_par  = (const float*)d_in[8];
    const float* out_w  = (const float*)d_in[9];
    float* outp = (float*)d_out;

    char* p = (char*)d_ws;
    auto alloc = [&](size_t bytes) { char* r = p; p += (bytes + 255) & ~(size_t)255; return r; };
    unsigned short* z_bf    = (unsigned short*)alloc((size_t)BLROWS*DM*2);
    unsigned short* xc_bf   = (unsigned short*)alloc((size_t)BLROWS*DI*2);
    unsigned short* y_bf    = (unsigned short*)alloc((size_t)BLROWS*DI*2);
    unsigned short* inw_bf  = (unsigned short*)alloc((size_t)2*1024*256*2);
    unsigned short* outw_bf = (unsigned short*)alloc((size_t)2*256*512*2);
    unsigned short* xpw_bf  = (unsigned short*)alloc((size_t)2*64*512*2);
    float* xz     = (float*)alloc((size_t)BLROWS*1024*4);
    float* x_conv = (float*)alloc((size_t)BLROWS*DI*4);
    float* x_dbl  = (float*)alloc((size_t)BLROWS*64*4);
    float* dtbuf  = (float*)alloc((size_t)BLROWS*DI*4);
    float* Pbuf   = (float*)alloc((size_t)BATCH*NCH*DI*DS*4);
    float* Sbuf   = (float*)alloc((size_t)BATCH*NCH*DI*DS*4);
    float* Hbuf   = (float*)alloc((size_t)BATCH*NCH*DI*DS*4);
    float* z_next = (float*)alloc((size_t)BLROWS*DM*4);

    /* weight casts (once per launch) */
    cast_f32_bf16_k<<<(2*1024*256)/256, 256, 0, stream>>>(in_w, inw_bf, 2*1024*256);
    cast_f32_bf16_k<<<(2*256*512)/256, 256, 0, stream>>>(out_w, outw_bf, 2*256*512);
    cast_xp_pad_k<<<(2*64*512)/256, 256, 0, stream>>>(xp_w, xpw_bf);

    const float* zcur = z_in;
    for (int l = 0; l < 2; ++l) {
        cast_f32_bf16_k<<<(BLROWS*DM)/256, 256, 0, stream>>>(zcur, z_bf, BLROWS*DM);
        /* in_proj: [8192,1024] = z[8192,256] @ in_w[1024,256]^T */
        gemm_bt_k<<<dim3(BLROWS/64, 1024/64), 256, 0, stream>>>(
            (const __bf16*)z_bf, (const __bf16*)(inw_bf + (size_t)l*1024*256),
            xz, BLROWS, 1024, 256);
        conv_silu_k<<<(BLROWS*DI)/256, 256, 0, stream>>>(
            xz, conv_w + (size_t)l*DI*4, conv_b + (size_t)l*DI, x_conv, xc_bf);
        /* x_proj (padded to 64 outputs): [8192,64] = xc[8192,512] @ xpw[64,512]^T */
        gemm_bt_k<<<dim3(BLROWS/64, 1), 256, 0, stream>>>(
            (const __bf16*)xc_bf, (const __bf16*)(xpw_bf + (size_t)l*64*512),
            x_dbl, BLROWS, 64, 512);
        dt_k<<<(BLROWS*DI)/256, 256, 0, stream>>>(
            x_dbl, dt_w + (size_t)l*DI*DTR, dt_b + (size_t)l*DI, dtbuf);
        scanA_k<<<dim3(DI/256, NCH, BATCH), 256, 0, stream>>>(
            dtbuf, x_conv, x_dbl, A_log + (size_t)l*DI*DS, Pbuf, Sbuf);
        scanB_k<<<(BATCH*DI*DS/4)/256, 256, 0, stream>>>(Pbuf, Sbuf, Hbuf);
        scanC_k<<<dim3(DI/256, NCH, BATCH), 256, 0, stream>>>(
            dtbuf, x_conv, x_dbl, Hbuf, A_log + (size_t)l*DI*DS,
            D_par + (size_t)l*DI, xz, y_bf);
        /* out_proj: [8192,256] = y[8192,512] @ out_w[256,512]^T */
        gemm_bt_k<<<dim3(BLROWS/64, 256/64), 256, 0, stream>>>(
            (const __bf16*)y_bf, (const __bf16*)(outw_bf + (size_t)l*256*512),
            (l == 0) ? z_next : outp, BLROWS, 256, 512);
        zcur = z_next;
    }
}